// Round 1
// baseline (3820.761 us; speedup 1.0000x reference)
//
#include <hip/hip_runtime.h>
#include <math.h>

#define NP    7056
#define NPS   84
#define CCH   4
#define HW    49
#define HWR   784
#define KF    196    // CCH*HW
#define NA    10
#define SLR   256
#define SHR   1024
#define GK    17
#define LDSS  68     // LDS row stride for [28][64] tiles (16B-aligned, low conflict)

// ---------------- separable gaussian blur (only at subsampled points) ----------------
__global__ void hpass_kernel(const float* __restrict__ hr, float* __restrict__ htmp) {
    __shared__ float g[GK];
    int tid = threadIdx.x;
    if (tid < GK) {
        double s = 0.0, mine = 0.0;
        for (int k = 0; k < GK; k++) {
            double ax = (double)k - 8.0;
            double e = exp(-ax * ax / 32.0);
            s += e;
            if (k == tid) mine = e;
        }
        g[tid] = (float)(mine / s);
    }
    __syncthreads();
    int gid = blockIdx.x * 256 + tid;      // 4*1024*256 exact
    int xs = gid & 255;
    int y  = (gid >> 8) & 1023;
    int c  = gid >> 18;
    const float* row = hr + (size_t)(c * 1024 + y) * 1024;
    int xb = xs * 4 - 6;                   // xs*4+2 - 8
    float acc = 0.f;
#pragma unroll
    for (int k = 0; k < GK; k++) {
        int xc = xb + k;
        float v = (xc >= 0 && xc < 1024) ? row[xc] : 0.f;
        acc = fmaf(g[k], v, acc);
    }
    htmp[gid] = acc;                       // [c][y][xs]
}

__global__ void vpass_kernel(const float* __restrict__ htmp, const float* __restrict__ ms,
                             float* __restrict__ diff) {
    __shared__ float g[GK];
    int tid = threadIdx.x;
    if (tid < GK) {
        double s = 0.0, mine = 0.0;
        for (int k = 0; k < GK; k++) {
            double ax = (double)k - 8.0;
            double e = exp(-ax * ax / 32.0);
            s += e;
            if (k == tid) mine = e;
        }
        g[tid] = (float)(mine / s);
    }
    __syncthreads();
    int gid = blockIdx.x * 256 + tid;      // 4*256*256 exact
    int xs = gid & 255;
    int ys = (gid >> 8) & 255;
    int c  = gid >> 16;
    int yb = ys * 4 - 6;
    float acc = 0.f;
#pragma unroll
    for (int k = 0; k < GK; k++) {
        int yc = yb + k;
        float v = (yc >= 0 && yc < 1024) ? htmp[(size_t)(c * 1024 + yc) * 256 + xs] : 0.f;
        acc = fmaf(g[k], v, acc);
    }
    diff[gid] = ms[gid] - acc;             // [c][ys][xs]
}

// ---------------- unfold residual patches: y[b=n*4+c][p] ----------------
__global__ void build_y_kernel(const float* __restrict__ diff, float* __restrict__ yb) {
    int gid = blockIdx.x * 256 + threadIdx.x;
    if (gid >= NP * CCH * HW) return;
    int p = gid % HW;
    int b = gid / HW;
    int c = b & 3;
    int n = b >> 2;
    int py = n / NPS, px = n % NPS;
    int dy = p / 7, dx = p % 7;
    yb[gid] = diff[(size_t)(c * SLR + py * 3 + dy) * SLR + px * 3 + dx];
}

// ---------------- fused corr GEMM + row argmax (fp32) ----------------
__device__ __forceinline__ unsigned long long shfl_xor_u64(unsigned long long v, int m) {
    unsigned int lo = (unsigned int)v;
    unsigned int hi = (unsigned int)(v >> 32);
    lo = __shfl_xor(lo, m, 64);
    hi = __shfl_xor(hi, m, 64);
    return ((unsigned long long)hi << 32) | (unsigned long long)lo;
}

__global__ __launch_bounds__(256) void gemm_argmax_kernel(
    const float* __restrict__ res, const float* __restrict__ dict,
    unsigned long long* __restrict__ keys) {
    __shared__ float As[28 * LDSS];
    __shared__ float Bs[28 * LDSS];
    int tid = threadIdx.x;
    int row0 = blockIdx.y * 64;
    int col0 = blockIdx.x * 64;
    int tx = tid & 15, ty = tid >> 4;
    float acc[4][4] = {{0.f}};

    int rr[7], kk7[7];
#pragma unroll
    for (int q = 0; q < 7; q++) {
        int e = q * 256 + tid;             // 1792 = 64 rows * 28 k
        rr[q] = e / 28;
        kk7[q] = e - rr[q] * 28;
    }

    for (int kc = 0; kc < KF; kc += 28) {
        float av[7], bv[7];
#pragma unroll
        for (int q = 0; q < 7; q++) {
            int gr = row0 + rr[q];
            int gc = col0 + rr[q];
            int col = kc + kk7[q];
            av[q] = (gr < NP) ? res[(size_t)gr * KF + col] : 0.f;
            bv[q] = (gc < NP) ? dict[(size_t)gc * KF + col] : 0.f;
        }
        __syncthreads();                   // previous chunk's compute done
#pragma unroll
        for (int q = 0; q < 7; q++) {
            As[kk7[q] * LDSS + rr[q]] = av[q];
            Bs[kk7[q] * LDSS + rr[q]] = bv[q];
        }
        __syncthreads();
#pragma unroll
        for (int k = 0; k < 28; k++) {
            float4 a4 = *(const float4*)&As[k * LDSS + ty * 4];
            float4 b4 = *(const float4*)&Bs[k * LDSS + tx * 4];
            float aa[4] = {a4.x, a4.y, a4.z, a4.w};
            float bb[4] = {b4.x, b4.y, b4.z, b4.w};
#pragma unroll
            for (int u = 0; u < 4; u++)
#pragma unroll
                for (int v = 0; v < 4; v++)
                    acc[u][v] = fmaf(aa[u], bb[v], acc[u][v]);
        }
    }

    // argmax epilogue: key = (bits(|corr|)<<32) | (0xFFFFFFFF - j)  -> first-occurrence ties
#pragma unroll
    for (int u = 0; u < 4; u++) {
        int gr = row0 + ty * 4 + u;
        unsigned long long key = 0ull;
#pragma unroll
        for (int v = 0; v < 4; v++) {
            int gc = col0 + tx * 4 + v;
            if (gc < NP) {
                unsigned int bits = __float_as_uint(fabsf(acc[u][v]));
                unsigned long long k2 = ((unsigned long long)bits << 32) |
                                        (unsigned long long)(0xFFFFFFFFu - (unsigned int)gc);
                key = (k2 > key) ? k2 : key;
            }
        }
#pragma unroll
        for (int m = 1; m < 16; m <<= 1) {
            unsigned long long o = shfl_xor_u64(key, m);
            key = (o > key) ? o : key;
        }
        if (tx == 0 && gr < NP) atomicMax(keys + gr, key);
    }
}

__global__ void decode_kernel(const unsigned long long* __restrict__ keys,
                              int* __restrict__ idxb, int col) {
    int n = blockIdx.x * 256 + threadIdx.x;
    if (n >= NP) return;
    idxb[n * NA + col] = (int)(0xFFFFFFFFu - (unsigned int)(keys[n] & 0xFFFFFFFFull));
}

// ---------------- per-(patch,channel) least squares via Cholesky ----------------
template <int M>
__global__ __launch_bounds__(256) void solve_kernel(
    const float* __restrict__ yb, const float* __restrict__ dict,
    int* __restrict__ idxb, float* __restrict__ alphab, float* __restrict__ resb) {
    int b = blockIdx.x * 256 + threadIdx.x;
    if (b >= NP * CCH) return;
    int n = b >> 2, c = b & 3;
    if (M == 1 && c == 0) idxb[n * NA] = n;   // index[:,0] = arange

    int id[M];
#pragma unroll
    for (int k = 0; k < M; k++) id[k] = (k == 0) ? n : idxb[n * NA + k];

    const float* yrow = yb + (size_t)b * HW;
    const int base_c = c * HW;

    constexpr int TRI = M * (M + 1) / 2;
    float G[TRI];
    float rhs[M];
#pragma unroll
    for (int t = 0; t < TRI; t++) G[t] = 0.f;
#pragma unroll
    for (int k = 0; k < M; k++) rhs[k] = 0.f;

#pragma unroll
    for (int p0 = 0; p0 < HW; p0 += 7) {
        float a[M][7];
#pragma unroll
        for (int k = 0; k < M; k++) {
            const float* dr = dict + (size_t)id[k] * KF + base_c + p0;
#pragma unroll
            for (int j = 0; j < 7; j++) a[k][j] = dr[j];
        }
#pragma unroll
        for (int j = 0; j < 7; j++) {
            float yp = yrow[p0 + j];
#pragma unroll
            for (int k = 0; k < M; k++) {
                rhs[k] = fmaf(a[k][j], yp, rhs[k]);
#pragma unroll
                for (int l = 0; l <= k; l++)
                    G[k * (k + 1) / 2 + l] = fmaf(a[k][j], a[l][j], G[k * (k + 1) / 2 + l]);
            }
        }
    }

    // Cholesky in place; store inverse diagonal
#pragma unroll
    for (int k = 0; k < M; k++) {
        float s = G[k * (k + 1) / 2 + k];
#pragma unroll
        for (int j = 0; j < k; j++) {
            float l = G[k * (k + 1) / 2 + j];
            s = fmaf(-l, l, s);
        }
        float inv = 1.0f / sqrtf(fmaxf(s, 1e-30f));
        G[k * (k + 1) / 2 + k] = inv;
#pragma unroll
        for (int r = k + 1; r < M; r++) {
            float t = G[r * (r + 1) / 2 + k];
#pragma unroll
            for (int j = 0; j < k; j++)
                t = fmaf(-G[r * (r + 1) / 2 + j], G[k * (k + 1) / 2 + j], t);
            G[r * (r + 1) / 2 + k] = t * inv;
        }
    }
    // forward: L z = rhs
#pragma unroll
    for (int k = 0; k < M; k++) {
        float t = rhs[k];
#pragma unroll
        for (int j = 0; j < k; j++) t = fmaf(-G[k * (k + 1) / 2 + j], rhs[j], t);
        rhs[k] = t * G[k * (k + 1) / 2 + k];
    }
    // backward: L^T alpha = z
#pragma unroll
    for (int k = M - 1; k >= 0; k--) {
        float t = rhs[k];
#pragma unroll
        for (int j = k + 1; j < M; j++) t = fmaf(-G[j * (j + 1) / 2 + k], rhs[j], t);
        rhs[k] = t * G[k * (k + 1) / 2 + k];
    }

#pragma unroll
    for (int k = 0; k < M; k++) alphab[(size_t)b * NA + k] = rhs[k];

    // residual res = y - A alpha
    for (int p = 0; p < HW; p++) {
        float s = yrow[p];
#pragma unroll
        for (int k = 0; k < M; k++)
            s = fmaf(-rhs[k], dict[(size_t)id[k] * KF + base_c + p], s);
        resb[(size_t)b * HW + p] = s;
    }
}

// ---------------- reconstruction + fold (gather overlap-add) + finalize ----------------
__global__ __launch_bounds__(256) void fold_final_kernel(
    const float* __restrict__ alphab, const int* __restrict__ idxb,
    const float* __restrict__ hr_dict, const float* __restrict__ divisor,
    const float* __restrict__ hrms, const float* __restrict__ lms,
    float* __restrict__ out) {
    int gid = blockIdx.x * 256 + threadIdx.x;  // 4*1024*1024 exact
    int x  = gid & 1023;
    int yy = (gid >> 10) & 1023;
    int c  = gid >> 20;

    int t0 = yy - 27;
    int py0 = (t0 > 0) ? (t0 + 11) / 12 : 0;
    int py1 = min(83, yy / 12);
    int s0 = x - 27;
    int px0 = (s0 > 0) ? (s0 + 11) / 12 : 0;
    int px1 = min(83, x / 12);

    float acc = 0.f;
    for (int py = py0; py <= py1; py++) {
        int qy = yy - py * 12;
        for (int px = px0; px <= px1; px++) {
            int qx = x - px * 12;
            int n = py * NPS + px;
            const float* al = alphab + (size_t)(n * CCH + c) * NA;
            const int* idn = idxb + n * NA;
            int q = qy * 28 + qx;
            float s = 0.f;
#pragma unroll
            for (int k = 0; k < NA; k++)
                s = fmaf(al[k], hr_dict[(size_t)idn[k] * (CCH * HWR) + c * HWR + q], s);
            acc += s;
        }
    }
    out[gid] = acc / (divisor[gid] + 1e-8f) + hrms[gid] + lms[gid];
}

// ---------------- launch ----------------
extern "C" void kernel_launch(void* const* d_in, const int* in_sizes, int n_in,
                              void* d_out, int out_size, void* d_ws, size_t ws_size,
                              hipStream_t stream) {
    const float* hrms    = (const float*)d_in[0];
    const float* ms      = (const float*)d_in[1];
    const float* lms     = (const float*)d_in[2];
    const float* lr_dict = (const float*)d_in[3];
    const float* hr_dict = (const float*)d_in[4];
    const float* divisor = (const float*)d_in[5];
    float* out = (float*)d_out;

    char* ws = (char*)d_ws;
    size_t off = 0;
    auto alloc = [&](size_t bytes) -> void* {
        void* p = ws + off;
        off += (bytes + 255) & ~(size_t)255;
        return p;
    };
    float* htmp   = (float*)alloc((size_t)4 * 1024 * 256 * 4);
    float* diff   = (float*)alloc((size_t)4 * 256 * 256 * 4);
    float* yb     = (float*)alloc((size_t)NP * CCH * HW * 4);
    float* resb   = (float*)alloc((size_t)NP * CCH * HW * 4);
    float* alphab = (float*)alloc((size_t)NP * CCH * NA * 4);
    int*   idxb   = (int*)alloc((size_t)NP * NA * 4);
    unsigned long long* keys = (unsigned long long*)alloc((size_t)NP * 8);

    hpass_kernel<<<4096, 256, 0, stream>>>(hrms, htmp);
    vpass_kernel<<<1024, 256, 0, stream>>>(htmp, ms, diff);
    build_y_kernel<<<(NP * CCH * HW + 255) / 256, 256, 0, stream>>>(diff, yb);

    dim3 gg((NP + 63) / 64, (NP + 63) / 64);
    for (int i = 0; i < NA; i++) {
        if (i > 0) {
            hipMemsetAsync(keys, 0, (size_t)NP * 8, stream);
            gemm_argmax_kernel<<<gg, 256, 0, stream>>>(resb, lr_dict, keys);
            decode_kernel<<<(NP + 255) / 256, 256, 0, stream>>>(keys, idxb, i);
        }
        int blocks = (NP * CCH + 255) / 256;
        switch (i + 1) {
            case 1:  solve_kernel<1><<<blocks, 256, 0, stream>>>(yb, lr_dict, idxb, alphab, resb); break;
            case 2:  solve_kernel<2><<<blocks, 256, 0, stream>>>(yb, lr_dict, idxb, alphab, resb); break;
            case 3:  solve_kernel<3><<<blocks, 256, 0, stream>>>(yb, lr_dict, idxb, alphab, resb); break;
            case 4:  solve_kernel<4><<<blocks, 256, 0, stream>>>(yb, lr_dict, idxb, alphab, resb); break;
            case 5:  solve_kernel<5><<<blocks, 256, 0, stream>>>(yb, lr_dict, idxb, alphab, resb); break;
            case 6:  solve_kernel<6><<<blocks, 256, 0, stream>>>(yb, lr_dict, idxb, alphab, resb); break;
            case 7:  solve_kernel<7><<<blocks, 256, 0, stream>>>(yb, lr_dict, idxb, alphab, resb); break;
            case 8:  solve_kernel<8><<<blocks, 256, 0, stream>>>(yb, lr_dict, idxb, alphab, resb); break;
            case 9:  solve_kernel<9><<<blocks, 256, 0, stream>>>(yb, lr_dict, idxb, alphab, resb); break;
            case 10: solve_kernel<10><<<blocks, 256, 0, stream>>>(yb, lr_dict, idxb, alphab, resb); break;
        }
    }

    fold_final_kernel<<<(4 * 1024 * 1024) / 256, 256, 0, stream>>>(
        alphab, idxb, hr_dict, divisor, hrms, lms, out);
}

// Round 2
// 1882.652 us; speedup vs baseline: 2.0295x; 2.0295x over previous
//
#include <hip/hip_runtime.h>
#include <math.h>

#define NP    7056
#define NPS   84
#define CCH   4
#define HW    49
#define HWR   784
#define KF    196    // CCH*HW
#define KP    224    // KF padded to multiple of 32
#define NA    10
#define SLR   256
#define SHR   1024
#define GK    17

typedef _Float16 half8 __attribute__((ext_vector_type(8)));
typedef float f32x4 __attribute__((ext_vector_type(4)));

// ---------------- separable gaussian blur (only at subsampled points) ----------------
__global__ void hpass_kernel(const float* __restrict__ hr, float* __restrict__ htmp) {
    __shared__ float g[GK];
    int tid = threadIdx.x;
    if (tid < GK) {
        double s = 0.0, mine = 0.0;
        for (int k = 0; k < GK; k++) {
            double ax = (double)k - 8.0;
            double e = exp(-ax * ax / 32.0);
            s += e;
            if (k == tid) mine = e;
        }
        g[tid] = (float)(mine / s);
    }
    __syncthreads();
    int gid = blockIdx.x * 256 + tid;      // 4*1024*256 exact
    int xs = gid & 255;
    int y  = (gid >> 8) & 1023;
    int c  = gid >> 18;
    const float* row = hr + (size_t)(c * 1024 + y) * 1024;
    int xb = xs * 4 - 6;                   // xs*4+2 - 8
    float acc = 0.f;
#pragma unroll
    for (int k = 0; k < GK; k++) {
        int xc = xb + k;
        float v = (xc >= 0 && xc < 1024) ? row[xc] : 0.f;
        acc = fmaf(g[k], v, acc);
    }
    htmp[gid] = acc;                       // [c][y][xs]
}

__global__ void vpass_kernel(const float* __restrict__ htmp, const float* __restrict__ ms,
                             float* __restrict__ diff) {
    __shared__ float g[GK];
    int tid = threadIdx.x;
    if (tid < GK) {
        double s = 0.0, mine = 0.0;
        for (int k = 0; k < GK; k++) {
            double ax = (double)k - 8.0;
            double e = exp(-ax * ax / 32.0);
            s += e;
            if (k == tid) mine = e;
        }
        g[tid] = (float)(mine / s);
    }
    __syncthreads();
    int gid = blockIdx.x * 256 + tid;      // 4*256*256 exact
    int xs = gid & 255;
    int ys = (gid >> 8) & 255;
    int c  = gid >> 16;
    int yb = ys * 4 - 6;
    float acc = 0.f;
#pragma unroll
    for (int k = 0; k < GK; k++) {
        int yc = yb + k;
        float v = (yc >= 0 && yc < 1024) ? htmp[(size_t)(c * 1024 + yc) * 256 + xs] : 0.f;
        acc = fmaf(g[k], v, acc);
    }
    diff[gid] = ms[gid] - acc;             // [c][ys][xs]
}

// ---------------- unfold residual patches: y[b=n*4+c][p] ----------------
__global__ void build_y_kernel(const float* __restrict__ diff, float* __restrict__ yb) {
    int gid = blockIdx.x * 256 + threadIdx.x;
    if (gid >= NP * CCH * HW) return;
    int p = gid % HW;
    int b = gid / HW;
    int c = b & 3;
    int n = b >> 2;
    int py = n / NPS, px = n % NPS;
    int dy = p / 7, dx = p % 7;
    yb[gid] = diff[(size_t)(c * SLR + py * 3 + dy) * SLR + px * 3 + dx];
}

// ---------------- fp32 -> fp16 hi/lo split (with K padding) ----------------
__global__ void split_kernel(const float* __restrict__ src, _Float16* __restrict__ h,
                             _Float16* __restrict__ l) {
    int gid = blockIdx.x * 256 + threadIdx.x;
    if (gid >= NP * KP) return;
    int r = gid / KP, k = gid - r * KP;
    float x = (k < KF) ? src[(size_t)r * KF + k] : 0.f;
    _Float16 hi = (_Float16)x;
    h[gid] = hi;
    l[gid] = (_Float16)(x - (float)hi);
}

// ---------------- MFMA corr GEMM + row argmax (split-fp16, fp32 acc) ----------------
__device__ __forceinline__ unsigned long long shfl_xor_u64(unsigned long long v, int m) {
    unsigned int lo = (unsigned int)v;
    unsigned int hi = (unsigned int)(v >> 32);
    lo = __shfl_xor(lo, m, 64);
    hi = __shfl_xor(hi, m, 64);
    return ((unsigned long long)hi << 32) | (unsigned long long)lo;
}

// XOR-swizzle byte offset within an 8KB [128 rows][32 k] fp16 tile:
// flip bits 4-6 with row bits 0-2 (triangular linear map -> bijective).
__device__ __forceinline__ int swz(int a) { return a ^ (((a >> 6) & 7) << 4); }

__global__ __launch_bounds__(256) void mfma_argmax_kernel(
    const _Float16* __restrict__ Rh, const _Float16* __restrict__ Rl,
    const _Float16* __restrict__ Dh, const _Float16* __restrict__ Dl,
    unsigned long long* __restrict__ keys) {
    __shared__ __align__(16) char ldsb[4 * 8192];   // Ah | Al | Bh | Bl tiles
    int tid = threadIdx.x;
    int lane = tid & 63;
    int wave = tid >> 6;
    int wm = wave >> 1, wn = wave & 1;
    int row0 = blockIdx.y * 128;
    int col0 = blockIdx.x * 128;

    f32x4 acc[4][4];
#pragma unroll
    for (int u = 0; u < 4; u++)
#pragma unroll
        for (int v = 0; v < 4; v++) {
            f32x4 zz = {0.f, 0.f, 0.f, 0.f};
            acc[u][v] = zz;
        }

    int srow = tid >> 1;            // 0..127: tile row staged by this thread
    int shalf = tid & 1;            // 16-half (32B) chunk within the 32-k row
    bool av = (row0 + srow) < NP;
    bool bv = (col0 + srow) < NP;
    size_t abase = (size_t)(row0 + srow) * KP + shalf * 16;
    size_t bbase = (size_t)(col0 + srow) * KP + shalf * 16;
    int nom = srow * 64 + shalf * 32;
    int w0 = swz(nom), w1 = swz(nom + 16);
    int lr = lane & 15, lk = lane >> 4;
    half8 z = {0, 0, 0, 0, 0, 0, 0, 0};

    for (int kc = 0; kc < KP; kc += 32) {
        half8 vah0 = av ? *(const half8*)(Rh + abase + kc) : z;
        half8 vah1 = av ? *(const half8*)(Rh + abase + kc + 8) : z;
        half8 val0 = av ? *(const half8*)(Rl + abase + kc) : z;
        half8 val1 = av ? *(const half8*)(Rl + abase + kc + 8) : z;
        half8 vbh0 = bv ? *(const half8*)(Dh + bbase + kc) : z;
        half8 vbh1 = bv ? *(const half8*)(Dh + bbase + kc + 8) : z;
        half8 vbl0 = bv ? *(const half8*)(Dl + bbase + kc) : z;
        half8 vbl1 = bv ? *(const half8*)(Dl + bbase + kc + 8) : z;
        __syncthreads();            // previous k-step's compute done
        *(half8*)(ldsb + 0 * 8192 + w0) = vah0;
        *(half8*)(ldsb + 0 * 8192 + w1) = vah1;
        *(half8*)(ldsb + 1 * 8192 + w0) = val0;
        *(half8*)(ldsb + 1 * 8192 + w1) = val1;
        *(half8*)(ldsb + 2 * 8192 + w0) = vbh0;
        *(half8*)(ldsb + 2 * 8192 + w1) = vbh1;
        *(half8*)(ldsb + 3 * 8192 + w0) = vbl0;
        *(half8*)(ldsb + 3 * 8192 + w1) = vbl1;
        __syncthreads();

        half8 aH[4], aL[4], bH[4], bL[4];
#pragma unroll
        for (int u = 0; u < 4; u++) {
            int ra = (wm * 64 + u * 16 + lr) * 64 + lk * 16;
            aH[u] = *(const half8*)(ldsb + 0 * 8192 + swz(ra));
            aL[u] = *(const half8*)(ldsb + 1 * 8192 + swz(ra));
            int rb = (wn * 64 + u * 16 + lr) * 64 + lk * 16;
            bH[u] = *(const half8*)(ldsb + 2 * 8192 + swz(rb));
            bL[u] = *(const half8*)(ldsb + 3 * 8192 + swz(rb));
        }
#pragma unroll
        for (int u = 0; u < 4; u++)
#pragma unroll
            for (int v = 0; v < 4; v++) {
                acc[u][v] = __builtin_amdgcn_mfma_f32_16x16x32_f16(aH[u], bH[v], acc[u][v], 0, 0, 0);
                acc[u][v] = __builtin_amdgcn_mfma_f32_16x16x32_f16(aH[u], bL[v], acc[u][v], 0, 0, 0);
                acc[u][v] = __builtin_amdgcn_mfma_f32_16x16x32_f16(aL[u], bH[v], acc[u][v], 0, 0, 0);
            }
    }

    // argmax epilogue: C/D layout col=lane&15, row=(lane>>4)*4+j  [m89-verified]
#pragma unroll
    for (int u = 0; u < 4; u++)
#pragma unroll
        for (int j = 0; j < 4; j++) {
            unsigned long long key = 0ull;
#pragma unroll
            for (int v = 0; v < 4; v++) {
                int gc = col0 + wn * 64 + v * 16 + lr;
                if (gc < NP) {
                    unsigned int bits = __float_as_uint(fabsf(acc[u][v][j]));
                    unsigned long long k2 = ((unsigned long long)bits << 32) |
                                            (unsigned long long)(0xFFFFFFFFu - (unsigned int)gc);
                    key = (k2 > key) ? k2 : key;
                }
            }
#pragma unroll
            for (int m = 1; m < 16; m <<= 1) {
                unsigned long long o = shfl_xor_u64(key, m);
                key = (o > key) ? o : key;
            }
            if (lr == 0) {
                int gr = row0 + wm * 64 + u * 16 + lk * 4 + j;
                if (gr < NP) atomicMax(keys + gr, key);
            }
        }
}

__global__ void decode_kernel(const unsigned long long* __restrict__ keys,
                              int* __restrict__ idxb, int col) {
    int n = blockIdx.x * 256 + threadIdx.x;
    if (n >= NP) return;
    idxb[n * NA + col] = (int)(0xFFFFFFFFu - (unsigned int)(keys[n] & 0xFFFFFFFFull));
}

// ---------------- per-(patch,channel) least squares via Cholesky ----------------
template <int M>
__global__ __launch_bounds__(256) void solve_kernel(
    const float* __restrict__ yb, const float* __restrict__ dict,
    int* __restrict__ idxb, float* __restrict__ alphab, float* __restrict__ resb) {
    int b = blockIdx.x * 256 + threadIdx.x;
    if (b >= NP * CCH) return;
    int n = b >> 2, c = b & 3;
    if (M == 1 && c == 0) idxb[n * NA] = n;   // index[:,0] = arange

    int id[M];
#pragma unroll
    for (int k = 0; k < M; k++) id[k] = (k == 0) ? n : idxb[n * NA + k];

    const float* yrow = yb + (size_t)b * HW;
    const int base_c = c * HW;

    constexpr int TRI = M * (M + 1) / 2;
    float G[TRI];
    float rhs[M];
#pragma unroll
    for (int t = 0; t < TRI; t++) G[t] = 0.f;
#pragma unroll
    for (int k = 0; k < M; k++) rhs[k] = 0.f;

#pragma unroll
    for (int p0 = 0; p0 < HW; p0 += 7) {
        float a[M][7];
#pragma unroll
        for (int k = 0; k < M; k++) {
            const float* dr = dict + (size_t)id[k] * KF + base_c + p0;
#pragma unroll
            for (int j = 0; j < 7; j++) a[k][j] = dr[j];
        }
#pragma unroll
        for (int j = 0; j < 7; j++) {
            float yp = yrow[p0 + j];
#pragma unroll
            for (int k = 0; k < M; k++) {
                rhs[k] = fmaf(a[k][j], yp, rhs[k]);
#pragma unroll
                for (int l = 0; l <= k; l++)
                    G[k * (k + 1) / 2 + l] = fmaf(a[k][j], a[l][j], G[k * (k + 1) / 2 + l]);
            }
        }
    }

    // Cholesky in place; store inverse diagonal
#pragma unroll
    for (int k = 0; k < M; k++) {
        float s = G[k * (k + 1) / 2 + k];
#pragma unroll
        for (int j = 0; j < k; j++) {
            float l = G[k * (k + 1) / 2 + j];
            s = fmaf(-l, l, s);
        }
        float inv = 1.0f / sqrtf(fmaxf(s, 1e-30f));
        G[k * (k + 1) / 2 + k] = inv;
#pragma unroll
        for (int r = k + 1; r < M; r++) {
            float t = G[r * (r + 1) / 2 + k];
#pragma unroll
            for (int j = 0; j < k; j++)
                t = fmaf(-G[r * (r + 1) / 2 + j], G[k * (k + 1) / 2 + j], t);
            G[r * (r + 1) / 2 + k] = t * inv;
        }
    }
    // forward: L z = rhs
#pragma unroll
    for (int k = 0; k < M; k++) {
        float t = rhs[k];
#pragma unroll
        for (int j = 0; j < k; j++) t = fmaf(-G[k * (k + 1) / 2 + j], rhs[j], t);
        rhs[k] = t * G[k * (k + 1) / 2 + k];
    }
    // backward: L^T alpha = z
#pragma unroll
    for (int k = M - 1; k >= 0; k--) {
        float t = rhs[k];
#pragma unroll
        for (int j = k + 1; j < M; j++) t = fmaf(-G[j * (j + 1) / 2 + k], rhs[j], t);
        rhs[k] = t * G[k * (k + 1) / 2 + k];
    }

#pragma unroll
    for (int k = 0; k < M; k++) alphab[(size_t)b * NA + k] = rhs[k];

    // residual res = y - A alpha
    for (int p = 0; p < HW; p++) {
        float s = yrow[p];
#pragma unroll
        for (int k = 0; k < M; k++)
            s = fmaf(-rhs[k], dict[(size_t)id[k] * KF + base_c + p], s);
        resb[(size_t)b * HW + p] = s;
    }
}

// ---------------- reconstruction + fold (gather overlap-add) + finalize ----------------
__global__ __launch_bounds__(256) void fold_final_kernel(
    const float* __restrict__ alphab, const int* __restrict__ idxb,
    const float* __restrict__ hr_dict, const float* __restrict__ divisor,
    const float* __restrict__ hrms, const float* __restrict__ lms,
    float* __restrict__ out) {
    int gid = blockIdx.x * 256 + threadIdx.x;  // 4*1024*1024 exact
    int x  = gid & 1023;
    int yy = (gid >> 10) & 1023;
    int c  = gid >> 20;

    int t0 = yy - 27;
    int py0 = (t0 > 0) ? (t0 + 11) / 12 : 0;
    int py1 = min(83, yy / 12);
    int s0 = x - 27;
    int px0 = (s0 > 0) ? (s0 + 11) / 12 : 0;
    int px1 = min(83, x / 12);

    float acc = 0.f;
    for (int py = py0; py <= py1; py++) {
        int qy = yy - py * 12;
        for (int px = px0; px <= px1; px++) {
            int qx = x - px * 12;
            int n = py * NPS + px;
            const float* al = alphab + (size_t)(n * CCH + c) * NA;
            const int* idn = idxb + n * NA;
            int q = qy * 28 + qx;
            float s = 0.f;
#pragma unroll
            for (int k = 0; k < NA; k++)
                s = fmaf(al[k], hr_dict[(size_t)idn[k] * (CCH * HWR) + c * HWR + q], s);
            acc += s;
        }
    }
    out[gid] = acc / (divisor[gid] + 1e-8f) + hrms[gid] + lms[gid];
}

// ---------------- launch ----------------
extern "C" void kernel_launch(void* const* d_in, const int* in_sizes, int n_in,
                              void* d_out, int out_size, void* d_ws, size_t ws_size,
                              hipStream_t stream) {
    const float* hrms    = (const float*)d_in[0];
    const float* ms      = (const float*)d_in[1];
    const float* lms     = (const float*)d_in[2];
    const float* lr_dict = (const float*)d_in[3];
    const float* hr_dict = (const float*)d_in[4];
    const float* divisor = (const float*)d_in[5];
    float* out = (float*)d_out;

    char* ws = (char*)d_ws;
    size_t off = 0;
    auto alloc = [&](size_t bytes) -> void* {
        void* p = ws + off;
        off += (bytes + 255) & ~(size_t)255;
        return p;
    };
    float* htmp   = (float*)alloc((size_t)4 * 1024 * 256 * 4);
    float* diff   = (float*)alloc((size_t)4 * 256 * 256 * 4);
    float* yb     = (float*)alloc((size_t)NP * CCH * HW * 4);
    float* resb   = (float*)alloc((size_t)NP * CCH * HW * 4);
    float* alphab = (float*)alloc((size_t)NP * CCH * NA * 4);
    int*   idxb   = (int*)alloc((size_t)NP * NA * 4);
    unsigned long long* keys = (unsigned long long*)alloc((size_t)NP * 8);
    _Float16* Dh = (_Float16*)alloc((size_t)NP * KP * 2);
    _Float16* Dl = (_Float16*)alloc((size_t)NP * KP * 2);
    _Float16* Rh = (_Float16*)alloc((size_t)NP * KP * 2);
    _Float16* Rl = (_Float16*)alloc((size_t)NP * KP * 2);

    hpass_kernel<<<4096, 256, 0, stream>>>(hrms, htmp);
    vpass_kernel<<<1024, 256, 0, stream>>>(htmp, ms, diff);
    build_y_kernel<<<(NP * CCH * HW + 255) / 256, 256, 0, stream>>>(diff, yb);
    split_kernel<<<(NP * KP + 255) / 256, 256, 0, stream>>>(lr_dict, Dh, Dl);

    dim3 gg(56, 56);
    for (int i = 0; i < NA; i++) {
        if (i > 0) {
            split_kernel<<<(NP * KP + 255) / 256, 256, 0, stream>>>(resb, Rh, Rl);
            hipMemsetAsync(keys, 0, (size_t)NP * 8, stream);
            mfma_argmax_kernel<<<gg, 256, 0, stream>>>(Rh, Rl, Dh, Dl, keys);
            decode_kernel<<<(NP + 255) / 256, 256, 0, stream>>>(keys, idxb, i);
        }
        int blocks = (NP * CCH + 255) / 256;
        switch (i + 1) {
            case 1:  solve_kernel<1><<<blocks, 256, 0, stream>>>(yb, lr_dict, idxb, alphab, resb); break;
            case 2:  solve_kernel<2><<<blocks, 256, 0, stream>>>(yb, lr_dict, idxb, alphab, resb); break;
            case 3:  solve_kernel<3><<<blocks, 256, 0, stream>>>(yb, lr_dict, idxb, alphab, resb); break;
            case 4:  solve_kernel<4><<<blocks, 256, 0, stream>>>(yb, lr_dict, idxb, alphab, resb); break;
            case 5:  solve_kernel<5><<<blocks, 256, 0, stream>>>(yb, lr_dict, idxb, alphab, resb); break;
            case 6:  solve_kernel<6><<<blocks, 256, 0, stream>>>(yb, lr_dict, idxb, alphab, resb); break;
            case 7:  solve_kernel<7><<<blocks, 256, 0, stream>>>(yb, lr_dict, idxb, alphab, resb); break;
            case 8:  solve_kernel<8><<<blocks, 256, 0, stream>>>(yb, lr_dict, idxb, alphab, resb); break;
            case 9:  solve_kernel<9><<<blocks, 256, 0, stream>>>(yb, lr_dict, idxb, alphab, resb); break;
            case 10: solve_kernel<10><<<blocks, 256, 0, stream>>>(yb, lr_dict, idxb, alphab, resb); break;
        }
    }

    fold_final_kernel<<<(4 * 1024 * 1024) / 256, 256, 0, stream>>>(
        alphab, idxb, hr_dict, divisor, hrms, lms, out);
}

// Round 3
// 1630.874 us; speedup vs baseline: 2.3428x; 1.1544x over previous
//
#include <hip/hip_runtime.h>
#include <math.h>

#define NP    7056
#define NP2   7168   // padded row count (56*128)
#define NPS   84
#define CCH   4
#define HW    49
#define HWR   784
#define KF    196    // CCH*HW
#define KP    224    // KF padded to multiple of 32
#define NA    10
#define SLR   256
#define SHR   1024
#define GK    17

typedef _Float16 half8 __attribute__((ext_vector_type(8)));
typedef float f32x4 __attribute__((ext_vector_type(4)));

// ---------------- separable gaussian blur (only at subsampled points) ----------------
__global__ void hpass_kernel(const float* __restrict__ hr, float* __restrict__ htmp) {
    __shared__ float g[GK];
    int tid = threadIdx.x;
    if (tid < GK) {
        double s = 0.0, mine = 0.0;
        for (int k = 0; k < GK; k++) {
            double ax = (double)k - 8.0;
            double e = exp(-ax * ax / 32.0);
            s += e;
            if (k == tid) mine = e;
        }
        g[tid] = (float)(mine / s);
    }
    __syncthreads();
    int gid = blockIdx.x * 256 + tid;      // 4*1024*256 exact
    int xs = gid & 255;
    int y  = (gid >> 8) & 1023;
    int c  = gid >> 18;
    const float* row = hr + (size_t)(c * 1024 + y) * 1024;
    int xb = xs * 4 - 6;                   // xs*4+2 - 8
    float acc = 0.f;
#pragma unroll
    for (int k = 0; k < GK; k++) {
        int xc = xb + k;
        float v = (xc >= 0 && xc < 1024) ? row[xc] : 0.f;
        acc = fmaf(g[k], v, acc);
    }
    htmp[gid] = acc;                       // [c][y][xs]
}

__global__ void vpass_kernel(const float* __restrict__ htmp, const float* __restrict__ ms,
                             float* __restrict__ diff) {
    __shared__ float g[GK];
    int tid = threadIdx.x;
    if (tid < GK) {
        double s = 0.0, mine = 0.0;
        for (int k = 0; k < GK; k++) {
            double ax = (double)k - 8.0;
            double e = exp(-ax * ax / 32.0);
            s += e;
            if (k == tid) mine = e;
        }
        g[tid] = (float)(mine / s);
    }
    __syncthreads();
    int gid = blockIdx.x * 256 + tid;      // 4*256*256 exact
    int xs = gid & 255;
    int ys = (gid >> 8) & 255;
    int c  = gid >> 16;
    int yb = ys * 4 - 6;
    float acc = 0.f;
#pragma unroll
    for (int k = 0; k < GK; k++) {
        int yc = yb + k;
        float v = (yc >= 0 && yc < 1024) ? htmp[(size_t)(c * 1024 + yc) * 256 + xs] : 0.f;
        acc = fmaf(g[k], v, acc);
    }
    diff[gid] = ms[gid] - acc;             // [c][ys][xs]
}

// ---------------- unfold residual patches: y[b=n*4+c][p] ----------------
__global__ void build_y_kernel(const float* __restrict__ diff, float* __restrict__ yb) {
    int gid = blockIdx.x * 256 + threadIdx.x;
    if (gid >= NP * CCH * HW) return;
    int p = gid % HW;
    int b = gid / HW;
    int c = b & 3;
    int n = b >> 2;
    int py = n / NPS, px = n % NPS;
    int dy = p / 7, dx = p % 7;
    yb[gid] = diff[(size_t)(c * SLR + py * 3 + dy) * SLR + px * 3 + dx];
}

// ---------------- fp32 -> fp16 hi/lo split of the dictionary (padded rows/cols zero) ----
__global__ void split_kernel(const float* __restrict__ src, _Float16* __restrict__ h,
                             _Float16* __restrict__ l) {
    int gid = blockIdx.x * 256 + threadIdx.x;   // NP2*KP exact
    int r = gid / KP, k = gid - r * KP;
    float x = (r < NP && k < KF) ? src[(size_t)r * KF + k] : 0.f;
    _Float16 hi = (_Float16)x;
    h[gid] = hi;
    l[gid] = (_Float16)(x - (float)hi);
}

// ---------------- MFMA corr GEMM + row argmax (split-fp16, fp32 acc) ----------------
__device__ __forceinline__ unsigned long long shfl_xor_u64(unsigned long long v, int m) {
    unsigned int lo = (unsigned int)v;
    unsigned int hi = (unsigned int)(v >> 32);
    lo = __shfl_xor(lo, m, 64);
    hi = __shfl_xor(hi, m, 64);
    return ((unsigned long long)hi << 32) | (unsigned long long)lo;
}

__device__ __forceinline__ void gload16(const void* g, void* l) {
    __builtin_amdgcn_global_load_lds((const __attribute__((address_space(1))) void*)(void*)g,
                                     (__attribute__((address_space(3))) void*)l, 16, 0, 0);
}

__global__ __launch_bounds__(256) void mfma_argmax_kernel(
    const _Float16* __restrict__ Rh, const _Float16* __restrict__ Rl,
    const _Float16* __restrict__ Dh, const _Float16* __restrict__ Dl,
    unsigned long long* __restrict__ keys) {
    __shared__ __align__(16) _Float16 ldsb[4 * 4096];   // Ah | Al | Bh | Bl, 8KB each, LINEAR
    int tid = threadIdx.x;
    int lane = tid & 63;
    int wave = tid >> 6;
    int wm = wave >> 1, wn = wave & 1;
    int row0 = blockIdx.y * 128;
    int col0 = blockIdx.x * 128;
    int lr = lane & 15, lk = lane >> 4;

    // wave w stages tile w: rows rbase+0..127 of its matrix, k cols [kc,kc+32)
    const _Float16* src = (wave == 0) ? Rh : (wave == 1) ? Rl : (wave == 2) ? Dh : Dl;
    int rbase = (wave < 2) ? row0 : col0;
    // chunk j (1KB): lane loads 16B: row = j*16 + (lane>>2), half-offset (lane&3)*8
    const _Float16* gsrc = src + (size_t)(rbase + (lane >> 2)) * KP + (lane & 3) * 8;

    f32x4 acc[4][4];
#pragma unroll
    for (int u = 0; u < 4; u++)
#pragma unroll
        for (int v = 0; v < 4; v++) {
            f32x4 zz = {0.f, 0.f, 0.f, 0.f};
            acc[u][v] = zz;
        }

    for (int kc = 0; kc < KP; kc += 32) {
#pragma unroll
        for (int j = 0; j < 8; j++)
            gload16(gsrc + (size_t)j * 16 * KP + kc, &ldsb[wave * 4096 + j * 512]);
        __syncthreads();                 // drains vmcnt -> all 4 tiles resident

        half8 aH[4], aL[4], bH[4], bL[4];
#pragma unroll
        for (int u = 0; u < 4; u++) {
            int ra = (wm * 64 + u * 16 + lr) * 32 + lk * 8;
            aH[u] = *(const half8*)&ldsb[0 * 4096 + ra];
            aL[u] = *(const half8*)&ldsb[1 * 4096 + ra];
            int rb = (wn * 64 + u * 16 + lr) * 32 + lk * 8;
            bH[u] = *(const half8*)&ldsb[2 * 4096 + rb];
            bL[u] = *(const half8*)&ldsb[3 * 4096 + rb];
        }
#pragma unroll
        for (int u = 0; u < 4; u++)
#pragma unroll
            for (int v = 0; v < 4; v++) {
                acc[u][v] = __builtin_amdgcn_mfma_f32_16x16x32_f16(aH[u], bH[v], acc[u][v], 0, 0, 0);
                acc[u][v] = __builtin_amdgcn_mfma_f32_16x16x32_f16(aH[u], bL[v], acc[u][v], 0, 0, 0);
                acc[u][v] = __builtin_amdgcn_mfma_f32_16x16x32_f16(aL[u], bH[v], acc[u][v], 0, 0, 0);
            }
        __syncthreads();                 // all waves done reading before next stage
    }

    // argmax epilogue: C/D layout col=lane&15, row=(lane>>4)*4+j  [m89-verified]
#pragma unroll
    for (int u = 0; u < 4; u++)
#pragma unroll
        for (int j = 0; j < 4; j++) {
            unsigned long long key = 0ull;
#pragma unroll
            for (int v = 0; v < 4; v++) {
                int gc = col0 + wn * 64 + v * 16 + lr;
                if (gc < NP) {
                    unsigned int bits = __float_as_uint(fabsf(acc[u][v][j]));
                    unsigned long long k2 = ((unsigned long long)bits << 32) |
                                            (unsigned long long)(0xFFFFFFFFu - (unsigned int)gc);
                    key = (k2 > key) ? k2 : key;
                }
            }
#pragma unroll
            for (int m = 1; m < 16; m <<= 1) {
                unsigned long long o = shfl_xor_u64(key, m);
                key = (o > key) ? o : key;
            }
            if (lr == 0) {
                int gr = row0 + wm * 64 + u * 16 + lk * 4 + j;
                if (gr < NP) atomicMax(keys + gr, key);
            }
        }
}

// ---------------- per-(patch,channel) least squares via Cholesky ----------------
// Fused: decodes the newest atom from `keys`, writes idxb, and emits the fp16
// hi/lo split of the residual directly (consumed by the next GEMM).
template <int M>
__global__ __launch_bounds__(256) void solve_kernel(
    const float* __restrict__ yb, const float* __restrict__ dict,
    const unsigned long long* __restrict__ keys,
    int* __restrict__ idxb, float* __restrict__ alphab,
    _Float16* __restrict__ Rh, _Float16* __restrict__ Rl) {
    int b = blockIdx.x * 256 + threadIdx.x;
    if (b >= NP * CCH) return;
    int n = b >> 2, c = b & 3;

    int newidx = 0;
    if (M >= 2) newidx = (int)(0xFFFFFFFFu - (unsigned int)(keys[n] & 0xFFFFFFFFull));
    if (c == 0) {
        if (M == 1) idxb[n * NA] = n;                // index[:,0] = arange
        else        idxb[n * NA + (M - 1)] = newidx;
    }

    int id[M];
#pragma unroll
    for (int k = 0; k < M; k++)
        id[k] = (k == 0) ? n : ((M >= 2 && k == M - 1) ? newidx : idxb[n * NA + k]);

    const float* yrow = yb + (size_t)b * HW;
    const int base_c = c * HW;

    constexpr int TRI = M * (M + 1) / 2;
    float G[TRI];
    float rhs[M];
#pragma unroll
    for (int t = 0; t < TRI; t++) G[t] = 0.f;
#pragma unroll
    for (int k = 0; k < M; k++) rhs[k] = 0.f;

#pragma unroll
    for (int p0 = 0; p0 < HW; p0 += 7) {
        float a[M][7];
#pragma unroll
        for (int k = 0; k < M; k++) {
            const float* dr = dict + (size_t)id[k] * KF + base_c + p0;
#pragma unroll
            for (int j = 0; j < 7; j++) a[k][j] = dr[j];
        }
#pragma unroll
        for (int j = 0; j < 7; j++) {
            float yp = yrow[p0 + j];
#pragma unroll
            for (int k = 0; k < M; k++) {
                rhs[k] = fmaf(a[k][j], yp, rhs[k]);
#pragma unroll
                for (int l = 0; l <= k; l++)
                    G[k * (k + 1) / 2 + l] = fmaf(a[k][j], a[l][j], G[k * (k + 1) / 2 + l]);
            }
        }
    }

    // Cholesky in place; store inverse diagonal
#pragma unroll
    for (int k = 0; k < M; k++) {
        float s = G[k * (k + 1) / 2 + k];
#pragma unroll
        for (int j = 0; j < k; j++) {
            float l = G[k * (k + 1) / 2 + j];
            s = fmaf(-l, l, s);
        }
        float inv = 1.0f / sqrtf(fmaxf(s, 1e-30f));
        G[k * (k + 1) / 2 + k] = inv;
#pragma unroll
        for (int r = k + 1; r < M; r++) {
            float t = G[r * (r + 1) / 2 + k];
#pragma unroll
            for (int j = 0; j < k; j++)
                t = fmaf(-G[r * (r + 1) / 2 + j], G[k * (k + 1) / 2 + j], t);
            G[r * (r + 1) / 2 + k] = t * inv;
        }
    }
    // forward: L z = rhs
#pragma unroll
    for (int k = 0; k < M; k++) {
        float t = rhs[k];
#pragma unroll
        for (int j = 0; j < k; j++) t = fmaf(-G[k * (k + 1) / 2 + j], rhs[j], t);
        rhs[k] = t * G[k * (k + 1) / 2 + k];
    }
    // backward: L^T alpha = z
#pragma unroll
    for (int k = M - 1; k >= 0; k--) {
        float t = rhs[k];
#pragma unroll
        for (int j = k + 1; j < M; j++) t = fmaf(-G[j * (j + 1) / 2 + k], rhs[j], t);
        rhs[k] = t * G[k * (k + 1) / 2 + k];
    }

#pragma unroll
    for (int k = 0; k < M; k++) alphab[(size_t)b * NA + k] = rhs[k];

    // residual -> fp16 hi/lo split, written straight into the GEMM operand
    if (M < NA) {
        _Float16* rh = Rh + (size_t)n * KP + base_c;
        _Float16* rl = Rl + (size_t)n * KP + base_c;
        for (int p = 0; p < HW; p++) {
            float s = yrow[p];
#pragma unroll
            for (int k = 0; k < M; k++)
                s = fmaf(-rhs[k], dict[(size_t)id[k] * KF + base_c + p], s);
            _Float16 hi = (_Float16)s;
            rh[p] = hi;
            rl[p] = (_Float16)(s - (float)hi);
        }
    }
}

// ---------------- stage A: per-patch HR reconstruction (coalesced GEMV) ----------------
__global__ __launch_bounds__(256) void recon_kernel(
    const float* __restrict__ alphab, const int* __restrict__ idxb,
    const float* __restrict__ hr_dict, _Float16* __restrict__ hr_p) {
    int n = blockIdx.x;
    int tid = threadIdx.x;
    __shared__ float al[CCH * NA];
    __shared__ int idn[NA];
    if (tid < CCH * NA) al[tid] = alphab[(size_t)n * CCH * NA + tid];
    if (tid < NA) idn[tid] = idxb[n * NA + tid];
    __syncthreads();
#pragma unroll
    for (int c = 0; c < CCH; c++) {
        for (int q = tid; q < HWR; q += 256) {
            float s = 0.f;
#pragma unroll
            for (int k = 0; k < NA; k++)
                s = fmaf(al[c * NA + k], hr_dict[(size_t)idn[k] * (CCH * HWR) + c * HWR + q], s);
            hr_p[(size_t)n * (CCH * HWR) + c * HWR + q] = (_Float16)s;
        }
    }
}

// ---------------- stage B: streaming fold + finalize ----------------
__global__ __launch_bounds__(256) void fold2_kernel(
    const _Float16* __restrict__ hr_p, const float* __restrict__ divisor,
    const float* __restrict__ hrms, const float* __restrict__ lms,
    float* __restrict__ out) {
    int gid = blockIdx.x * 256 + threadIdx.x;  // 4*1024*1024 exact
    int x  = gid & 1023;
    int yy = (gid >> 10) & 1023;
    int c  = gid >> 20;

    int t0 = yy - 27;
    int py0 = (t0 > 0) ? (t0 + 11) / 12 : 0;
    int py1 = min(83, yy / 12);
    int s0 = x - 27;
    int px0 = (s0 > 0) ? (s0 + 11) / 12 : 0;
    int px1 = min(83, x / 12);

    float acc = 0.f;
    for (int py = py0; py <= py1; py++) {
        int qy = yy - py * 12;
        for (int px = px0; px <= px1; px++) {
            int qx = x - px * 12;
            int n = py * NPS + px;
            acc += (float)hr_p[(size_t)n * (CCH * HWR) + c * HWR + qy * 28 + qx];
        }
    }
    out[gid] = acc / (divisor[gid] + 1e-8f) + hrms[gid] + lms[gid];
}

// ---------------- fallback one-stage fold (if ws too small for hr_p) ----------------
__global__ __launch_bounds__(256) void fold_final_kernel(
    const float* __restrict__ alphab, const int* __restrict__ idxb,
    const float* __restrict__ hr_dict, const float* __restrict__ divisor,
    const float* __restrict__ hrms, const float* __restrict__ lms,
    float* __restrict__ out) {
    int gid = blockIdx.x * 256 + threadIdx.x;
    int x  = gid & 1023;
    int yy = (gid >> 10) & 1023;
    int c  = gid >> 20;
    int t0 = yy - 27;
    int py0 = (t0 > 0) ? (t0 + 11) / 12 : 0;
    int py1 = min(83, yy / 12);
    int s0 = x - 27;
    int px0 = (s0 > 0) ? (s0 + 11) / 12 : 0;
    int px1 = min(83, x / 12);
    float acc = 0.f;
    for (int py = py0; py <= py1; py++) {
        int qy = yy - py * 12;
        for (int px = px0; px <= px1; px++) {
            int qx = x - px * 12;
            int n = py * NPS + px;
            const float* al = alphab + (size_t)(n * CCH + c) * NA;
            const int* idn = idxb + n * NA;
            int q = qy * 28 + qx;
            float s = 0.f;
#pragma unroll
            for (int k = 0; k < NA; k++)
                s = fmaf(al[k], hr_dict[(size_t)idn[k] * (CCH * HWR) + c * HWR + q], s);
            acc += s;
        }
    }
    out[gid] = acc / (divisor[gid] + 1e-8f) + hrms[gid] + lms[gid];
}

// ---------------- launch ----------------
extern "C" void kernel_launch(void* const* d_in, const int* in_sizes, int n_in,
                              void* d_out, int out_size, void* d_ws, size_t ws_size,
                              hipStream_t stream) {
    const float* hrms    = (const float*)d_in[0];
    const float* ms      = (const float*)d_in[1];
    const float* lms     = (const float*)d_in[2];
    const float* lr_dict = (const float*)d_in[3];
    const float* hr_dict = (const float*)d_in[4];
    const float* divisor = (const float*)d_in[5];
    float* out = (float*)d_out;

    char* ws = (char*)d_ws;
    size_t off = 0;
    auto alloc = [&](size_t bytes) -> void* {
        void* p = ws + off;
        off += (bytes + 255) & ~(size_t)255;
        return p;
    };
    float* htmp   = (float*)alloc((size_t)4 * 1024 * 256 * 4);
    float* diff   = (float*)alloc((size_t)4 * 256 * 256 * 4);
    float* yb     = (float*)alloc((size_t)NP * CCH * HW * 4);
    float* alphab = (float*)alloc((size_t)NP * CCH * NA * 4);
    int*   idxb   = (int*)alloc((size_t)NP * NA * 4);
    unsigned long long* keys = (unsigned long long*)alloc((size_t)NP * 8);
    _Float16* Dh = (_Float16*)alloc((size_t)NP2 * KP * 2);
    _Float16* Dl = (_Float16*)alloc((size_t)NP2 * KP * 2);
    _Float16* Rh = (_Float16*)alloc((size_t)NP2 * KP * 2);
    _Float16* Rl = (_Float16*)alloc((size_t)NP2 * KP * 2);
    _Float16* hr_p = (_Float16*)alloc((size_t)NP * CCH * HWR * 2);
    bool two_stage = (off <= ws_size);

    hpass_kernel<<<4096, 256, 0, stream>>>(hrms, htmp);
    vpass_kernel<<<1024, 256, 0, stream>>>(htmp, ms, diff);
    build_y_kernel<<<(NP * CCH * HW + 255) / 256, 256, 0, stream>>>(diff, yb);
    split_kernel<<<(NP2 * KP) / 256, 256, 0, stream>>>(lr_dict, Dh, Dl);
    hipMemsetAsync(Rh, 0, (size_t)NP2 * KP * 2, stream);
    hipMemsetAsync(Rl, 0, (size_t)NP2 * KP * 2, stream);

    dim3 gg(56, 56);
    int blocks = (NP * CCH + 255) / 256;
    for (int i = 0; i < NA; i++) {
        if (i > 0) {
            hipMemsetAsync(keys, 0, (size_t)NP * 8, stream);
            mfma_argmax_kernel<<<gg, 256, 0, stream>>>(Rh, Rl, Dh, Dl, keys);
        }
        switch (i + 1) {
            case 1:  solve_kernel<1><<<blocks, 256, 0, stream>>>(yb, lr_dict, keys, idxb, alphab, Rh, Rl); break;
            case 2:  solve_kernel<2><<<blocks, 256, 0, stream>>>(yb, lr_dict, keys, idxb, alphab, Rh, Rl); break;
            case 3:  solve_kernel<3><<<blocks, 256, 0, stream>>>(yb, lr_dict, keys, idxb, alphab, Rh, Rl); break;
            case 4:  solve_kernel<4><<<blocks, 256, 0, stream>>>(yb, lr_dict, keys, idxb, alphab, Rh, Rl); break;
            case 5:  solve_kernel<5><<<blocks, 256, 0, stream>>>(yb, lr_dict, keys, idxb, alphab, Rh, Rl); break;
            case 6:  solve_kernel<6><<<blocks, 256, 0, stream>>>(yb, lr_dict, keys, idxb, alphab, Rh, Rl); break;
            case 7:  solve_kernel<7><<<blocks, 256, 0, stream>>>(yb, lr_dict, keys, idxb, alphab, Rh, Rl); break;
            case 8:  solve_kernel<8><<<blocks, 256, 0, stream>>>(yb, lr_dict, keys, idxb, alphab, Rh, Rl); break;
            case 9:  solve_kernel<9><<<blocks, 256, 0, stream>>>(yb, lr_dict, keys, idxb, alphab, Rh, Rl); break;
            case 10: solve_kernel<10><<<blocks, 256, 0, stream>>>(yb, lr_dict, keys, idxb, alphab, Rh, Rl); break;
        }
    }

    if (two_stage) {
        recon_kernel<<<NP, 256, 0, stream>>>(alphab, idxb, hr_dict, hr_p);
        fold2_kernel<<<(4 * 1024 * 1024) / 256, 256, 0, stream>>>(hr_p, divisor, hrms, lms, out);
    } else {
        fold_final_kernel<<<(4 * 1024 * 1024) / 256, 256, 0, stream>>>(
            alphab, idxb, hr_dict, divisor, hrms, lms, out);
    }
}